// Round 14
// baseline (124.360 us; speedup 1.0000x reference)
//
#include <hip/hip_runtime.h>
#include <hip/hip_cooperative_groups.h>
#include <math.h>

namespace cg = cooperative_groups;

constexpr int B = 4, C = 64, H = 80, W = 80;
constexpr int HW = H * W;            // 6400
constexpr int NPIX = B * HW;         // 25600
constexpr int PXB = 16;              // pixels per stage1 tile
constexpr int NTILE1 = NPIX / PXB;   // 1600 stage1 tiles
constexpr int NTILE2 = NPIX / 64;    // 400 m2cv3 tiles

typedef unsigned u32;

static __device__ __forceinline__ float silu(float v) {
    float e = __expf(-v);
    return v * __builtin_amdgcn_rcpf(1.0f + e);
}

// ---- packed u16 helpers (both GLCM channels in one instruction) -----------
static __device__ __forceinline__ u32 pks(u32 a, u32 b){u32 d; asm("v_pk_sub_u16 %0,%1,%2":"=v"(d):"v"(a),"v"(b)); return d;}
static __device__ __forceinline__ u32 pka(u32 a, u32 b){u32 d; asm("v_pk_add_u16 %0,%1,%2":"=v"(d):"v"(a),"v"(b)); return d;}
static __device__ __forceinline__ u32 pkm(u32 a, u32 b){u32 d; asm("v_pk_mul_lo_u16 %0,%1,%2":"=v"(d):"v"(a),"v"(b)); return d;}
static __device__ __forceinline__ u32 pkmin(u32 a, u32 b){u32 d; asm("v_pk_min_u16 %0,%1,%2":"=v"(d):"v"(a),"v"(b)); return d;}
static __device__ __forceinline__ u32 pkmaxi(u32 a, u32 b){u32 d; asm("v_pk_max_i16 %0,%1,%2":"=v"(d):"v"(a),"v"(b)); return d;}
static __device__ __forceinline__ float cb0(u32 a){float f; asm("v_cvt_f32_ubyte0 %0,%1":"=v"(f):"v"(a)); return f;}
static __device__ __forceinline__ float cb2(u32 a){float f; asm("v_cvt_f32_ubyte2 %0,%1":"=v"(f):"v"(a)); return f;}

// byte shuffle/LUT and byte-sum
static __device__ __forceinline__ u32 permb(u32 hi, u32 lo, u32 sel){
    u32 d; asm("v_perm_b32 %0, %1, %2, %3" : "=v"(d) : "v"(hi), "v"(lo), "v"(sel)); return d;}
static __device__ __forceinline__ u32 sad8(u32 a, u32 b, u32 c){
    u32 d; asm("v_sad_u8 %0, %1, %2, %3" : "=v"(d) : "v"(a), "v"(b), "v"(c)); return d;}

// packed compare-exchange: both u16 halves sorted independently (2 channels)
static __device__ __forceinline__ void ce(u32 &x, u32 &y) {
    u32 mn, mx;
    asm("v_pk_min_u16 %0, %2, %3\n\t"
        "v_pk_max_u16 %1, %2, %3"
        : "=&v"(mn), "=v"(mx) : "v"(x), "v"(y));
    x = mn; y = mx;
}

// ---------------------------------------------------------------------------
// Shared GLCM+stage1 tile body (used by both the fused coop kernel and the
// standalone fallback kernel). All LDS passed by reference.
// ---------------------------------------------------------------------------
struct SmA {
    u32   qcell[32][3][18];                            // 6912 B
    float xs[PXB][76] __attribute__((aligned(16)));    // 4864 B
    float ws1[32][68] __attribute__((aligned(16)));    // 8704 B
    float ws2[32][68] __attribute__((aligned(16)));    // 8704 B
    float wsm1[16][32] __attribute__((aligned(16)));   // 2048 B
    float aT[PXB][33];                                 // 2112 B
    float red[8][PXB][4];                              // 2048 B
};
struct SmB {
    float ys[16][4][82];                               // 20992 B
    float a2[32][64];                                  // 8192 B
    float bs[32][64];                                  // 8192 B
};
union SmemU { SmA a; SmB b; };

static __device__ __forceinline__ void stage1_tile(
    SmA& sm, int t, int tile,
    const float* __restrict__ x,
    const float* __restrict__ s1, const float* __restrict__ b1,
    const float* __restrict__ s2, const float* __restrict__ b2,
    const float* __restrict__ sm1, const float* __restrict__ bm1,
    float* __restrict__ a, float* __restrict__ bbuf, float* __restrict__ y16) {
    const int p0g = tile * PXB;
    const int bb  = p0g / HW;
    const int hw0 = p0g - bb * HW;
    const int h0  = hw0 / W;
    const int c0g = hw0 - h0 * W;

    // ---- A1: quantize stencil cells once, pack both channels ----
    for (int e = t; e < 32 * 3 * 18; e += 512) {
        const int grp = e / 54;
        const int rem = e - grp * 54;
        const int row = rem / 18;
        const int col = rem - row * 18;
        int gr = h0 + row - 1;  gr = gr < 0 ? 0 : (gr > H - 1 ? H - 1 : gr);
        int gc = c0g + col - 1; gc = gc < 0 ? 0 : (gc > W - 1 ? W - 1 : gc);
        const float v0 = x[((size_t)(bb * C + grp * 2)) * HW + gr * W + gc];
        const float v1 = x[((size_t)(bb * C + grp * 2 + 1)) * HW + gr * W + gc];
        int q0 = (int)(v0 * 7.0f); q0 = q0 < 0 ? 0 : (q0 > 7 ? 7 : q0);
        int q1 = (int)(v1 * 7.0f); q1 = q1 < 0 ? 0 : (q1 > 7 ? 7 : q1);
        sm.qcell[grp][row][col] = (u32)q0 | ((u32)q1 << 16);
        if (row == 1 && col >= 1 && col <= 16) {
            sm.xs[col - 1][grp * 2]     = v0;
            sm.xs[col - 1][grp * 2 + 1] = v1;
        }
    }
    __syncthreads();

    // ---- A2: GLCM packed-u16 core (perm/sad LUT for contrast+homog) ----
    const int pxl = t & 15;
    const int grp = t >> 4;
    u32 qpk[9];
    #pragma unroll
    for (int r = 0; r < 3; ++r)
        #pragma unroll
        for (int k = 0; k < 3; ++k)
            qpk[r * 3 + k] = sm.qcell[grp][r][pxl + k];

    static constexpr int PA[20] = {0,1,3,4,6,7, 0,1,2,3,4,5, 0,1,3,4, 1,2,4,5};
    static constexpr int PB[20] = {1,2,4,5,7,8, 3,4,5,6,7,8, 4,5,7,8, 3,4,6,7};

    const u32 ONEpk = 0x00010001u, EIGHTpk = 0x00080008u;
    u32 key[20];
    u32 csI = 0, hloI = 0, hhiI = 0;
    const u32 z0 = 0;
    #pragma unroll
    for (int j = 0; j < 10; ++j) {
        u32 adp0, adp1;
        {
            const u32 qa = qpk[PA[2*j]], qb = qpk[PB[2*j]];
            const u32 d = pks(qa, qb);
            adp0 = pkmaxi(d, pks(0u, d));
            key[2*j] = pka(pkm(qa, EIGHTpk), qb);
        }
        {
            const u32 qa = qpk[PA[2*j+1]], qb = qpk[PB[2*j+1]];
            const u32 d = pks(qa, qb);
            adp1 = pkmaxi(d, pks(0u, d));
            key[2*j+1] = pka(pkm(qa, EIGHTpk), qb);
        }
        const u32 pk4 = permb(adp1, adp0, 0x06040200u);
        csI  = sad8(permb(0x31241910u, 0x09040100u, pk4), z0, csI);
        hloI = sad8(permb(0x69788CA8u, 0xD218A448u, pk4), z0, hloI);
        hhiI = sad8(permb(0x00000000u, 0x00010103u, pk4), z0, hhiI);
    }

    #pragma unroll
    for (int p = 1; p < 32; p <<= 1) {
        #pragma unroll
        for (int k = p; k >= 1; k >>= 1) {
            const int jm = k % p;
            #pragma unroll
            for (int lo = 0; lo < 20; ++lo) {
                const int hi = lo + k;
                if (hi < 20 && lo >= jm && ((lo - jm) % (2 * k)) < k &&
                    (lo / (2 * p)) == (hi / (2 * p))) {
                    ce(key[lo], key[hi]);
                }
            }
        }
    }

    u32 eq[20];
    #pragma unroll
    for (int ai = 1; ai < 20; ++ai)
        eq[ai] = pks(ONEpk, pkmin(pks(key[ai], key[ai - 1]), ONEpk));

    u32 pc = 0, ps = 0, pv[20];
    pv[0] = 0;
    #pragma unroll
    for (int ai = 1; ai < 20; ++ai) {
        pc = pkm(pka(pc, ONEpk), eq[ai]);
        pv[ai] = pc;
        ps = pka(ps, pc);
    }
    float pr0, pr1;
    {
        const u32 m = pka(pv[19], ONEpk);
        pr0 = cb0(m); pr1 = cb2(m);
    }
    u32 rc = 0;
    #pragma unroll
    for (int ai = 18; ai >= 0; --ai) {
        rc = pkm(pka(rc, ONEpk), eq[ai + 1]);
        const u32 m = pka(pka(pv[ai], rc), ONEpk);
        pr0 *= cb0(m); pr1 *= cb2(m);
    }

    const int psum = (int)(ps & 0xFFFFu) + (int)(ps >> 16);
    const float lsum = __logf(pr0) + __logf(pr1);

    float fc = (float)csI * (1.f / 20.f);
    float fe = ((float)psum * 2.f + 40.f) * (1.f / 400.f);
    float fn = -(lsum + 40.f * -2.9957322736f) * (1.f / 20.f);
    float fh = (float)(hloI + (hhiI << 8)) * (1.f / 16800.f);

    fc += __shfl_xor(fc, 16); fe += __shfl_xor(fe, 16);
    fn += __shfl_xor(fn, 16); fh += __shfl_xor(fh, 16);
    fc += __shfl_xor(fc, 32); fe += __shfl_xor(fe, 32);
    fn += __shfl_xor(fn, 32); fh += __shfl_xor(fh, 32);
    const int wv = t >> 6;
    if ((t & 63) < 16) {
        sm.red[wv][pxl][0] = fc; sm.red[wv][pxl][1] = fe;
        sm.red[wv][pxl][2] = fn; sm.red[wv][pxl][3] = fh;
    }
    __syncthreads();
    if (t < 64) {
        const int p2 = t >> 2, f = t & 3;
        float s = 0.f;
        #pragma unroll
        for (int wq = 0; wq < 8; ++wq) s += sm.red[wq][p2][f];
        sm.xs[p2][64 + f] = s * (1.f / 64.f);
    }
    __syncthreads();

    // ---- A3: cv1 + cv2, thread = (px, oc); float4 LDS reads ----
    {
        const int px = t & 15;
        const int oc = t >> 4;
        float acc1 = 0.f, acc2 = 0.f;
        #pragma unroll
        for (int k = 0; k < 17; ++k) {
            const float4 xv = *reinterpret_cast<const float4*>(&sm.xs[px][k * 4]);
            const float4 wa = *reinterpret_cast<const float4*>(&sm.ws1[oc][k * 4]);
            const float4 wb = *reinterpret_cast<const float4*>(&sm.ws2[oc][k * 4]);
            acc1 += xv.x * wa.x + xv.y * wa.y + xv.z * wa.z + xv.w * wa.w;
            acc2 += xv.x * wb.x + xv.y * wb.y + xv.z * wb.z + xv.w * wb.w;
        }
        const int hw2 = hw0 + px;
        const float v1 = silu(acc1 * s1[oc] + b1[oc]);
        a[((size_t)(bb * 32 + oc)) * HW + hw2] = v1;
        sm.aT[px][oc] = v1;
        bbuf[((size_t)(bb * 32 + oc)) * HW + hw2] = silu(acc2 * s2[oc] + b2[oc]);
    }
    __syncthreads();

    // ---- A4: m1, thread = (px, oc16), first 256 threads ----
    if (t < 256) {
        const int px = t & 15;
        const int oc = t >> 4;
        float acc = 0.f;
        #pragma unroll 8
        for (int ic = 0; ic < 32; ++ic)
            acc += sm.aT[px][ic] * sm.wsm1[oc][ic];
        y16[((size_t)(bb * 16 + oc)) * HW + hw0 + px] = silu(acc * sm1[oc] + bm1[oc]);
    }
}

static __device__ __forceinline__ void stage_weights(
    SmA& sm, int t,
    const float* __restrict__ w1, const float* __restrict__ w2,
    const float* __restrict__ wm1) {
    const float4* w1f = (const float4*)w1;
    const float4* w2f = (const float4*)w2;
    float4* s1f = (float4*)&sm.ws1[0][0];
    float4* s2f = (float4*)&sm.ws2[0][0];
    for (int e = t; e < 544; e += 512) { s1f[e] = w1f[e]; s2f[e] = w2f[e]; }
    if (t < 128) ((float4*)&sm.wsm1[0][0])[t] = ((const float4*)wm1)[t];
}

static __device__ __forceinline__ void m2cv3_tile(
    SmB& sm, int t, int tile,
    const float* __restrict__ y16, const float* __restrict__ a,
    const float* __restrict__ bbuf,
    const float* __restrict__ wm2, const float* __restrict__ sm2, const float* __restrict__ bm2,
    const float* __restrict__ wc, const float* __restrict__ sc, const float* __restrict__ bc,
    float* __restrict__ out) {
    const int p0 = tile * 64;
    const int bi = p0 / HW;
    const int hw0 = p0 - bi * HW;
    const int h0 = hw0 / W;

    const float* yb = y16 + (size_t)(bi * 16) * HW;
    for (int e = t; e < 16 * 4 * 82; e += 512) {
        const int ch = e / 328;
        const int rem = e - ch * 328;
        const int row = rem / 82;
        const int col = rem - row * 82;
        const int r = h0 - 1 + row;
        const int c = col - 1;
        float v = 0.f;
        if ((unsigned)r < (unsigned)H && (unsigned)c < (unsigned)W)
            v = yb[(size_t)ch * HW + r * W + c];
        sm.ys[ch][row][col] = v;
    }
    for (int e = t; e < 32 * 64; e += 512) {
        const int ic = e >> 6, px = e & 63;
        sm.bs[ic][px] = bbuf[((size_t)(bi * 32 + ic)) * HW + hw0 + px];
    }
    __syncthreads();

    const int lane = t & 63;
    const int wv = __builtin_amdgcn_readfirstlane(t >> 6);
    const int hw = hw0 + lane;
    const int h = hw / W;
    const int w = hw - h * W;
    const int lr = h - h0;
    const int oc0 = wv * 4;

    float acc[4] = {0.f, 0.f, 0.f, 0.f};
    #pragma unroll 2
    for (int ic = 0; ic < 16; ++ic) {
        #pragma unroll
        for (int ky = 0; ky < 3; ++ky) {
            #pragma unroll
            for (int kx = 0; kx < 3; ++kx) {
                const float v = sm.ys[ic][lr + ky][w + kx];
                const int tap = ic * 9 + ky * 3 + kx;
                #pragma unroll
                for (int j = 0; j < 4; ++j)
                    acc[j] += v * wm2[(oc0 + j) * 144 + tap];
            }
        }
    }
    #pragma unroll
    for (int j = 0; j < 4; ++j) {
        const int oc = oc0 + j;
        sm.a2[oc][lane] = a[((size_t)(bi * 32 + oc)) * HW + hw]
                        + silu(acc[j] * sm2[oc] + bm2[oc]);
    }
    __syncthreads();
    const int oc3 = wv * 8;
    float c_[8] = {0.f, 0.f, 0.f, 0.f, 0.f, 0.f, 0.f, 0.f};
    #pragma unroll 4
    for (int ic = 0; ic < 32; ++ic) {
        const float av = sm.a2[ic][lane];
        const float bv = sm.bs[ic][lane];
        #pragma unroll
        for (int j = 0; j < 8; ++j) {
            c_[j] += av * wc[(oc3 + j) * 64 + ic];
            c_[j] += bv * wc[(oc3 + j) * 64 + 32 + ic];
        }
    }
    #pragma unroll
    for (int j = 0; j < 8; ++j) {
        const int oc = oc3 + j;
        out[((size_t)(bi * 64 + oc)) * HW + hw] = silu(c_[j] * sc[oc] + bc[oc]);
    }
}

// ---------------------------------------------------------------------------
// Fused cooperative kernel: grid-stride phase A -> grid.sync -> grid-stride
// phase B. Grid size comes from the occupancy API at launch time (R13 lesson:
// hand-computed 800 was rejected — likely TooLarge after LDS rounding).
// ---------------------------------------------------------------------------
__global__ __launch_bounds__(512, 4) void fused_kernel(
    const float* __restrict__ x,
    const float* __restrict__ w1, const float* __restrict__ s1, const float* __restrict__ b1,
    const float* __restrict__ w2, const float* __restrict__ s2, const float* __restrict__ b2,
    const float* __restrict__ wm1, const float* __restrict__ sm1, const float* __restrict__ bm1,
    const float* __restrict__ wm2, const float* __restrict__ sm2, const float* __restrict__ bm2,
    const float* __restrict__ wc, const float* __restrict__ sc, const float* __restrict__ bc,
    float* __restrict__ a, float* __restrict__ bbuf, float* __restrict__ y16,
    float* __restrict__ out) {
    __shared__ SmemU sm;
    const int t = threadIdx.x;

    stage_weights(sm.a, t, w1, w2, wm1);
    for (int tile = blockIdx.x; tile < NTILE1; tile += gridDim.x) {
        __syncthreads();   // protect LDS from previous iteration readers
        stage1_tile(sm.a, t, tile, x, s1, b1, s2, b2, sm1, bm1, a, bbuf, y16);
    }

    cg::this_grid().sync();   // y16/a/bbuf complete (incl. halos)

    for (int tile = blockIdx.x; tile < NTILE2; tile += gridDim.x) {
        __syncthreads();
        m2cv3_tile(sm.b, t, tile, y16, a, bbuf, wm2, sm2, bm2, wc, sc, bc, out);
    }
}

// ---- fallback pair (two plain dispatches; identical math) ------------------
__global__ __launch_bounds__(512, 4) void stage1_kernel(
    const float* __restrict__ x,
    const float* __restrict__ w1, const float* __restrict__ s1, const float* __restrict__ b1,
    const float* __restrict__ w2, const float* __restrict__ s2, const float* __restrict__ b2,
    const float* __restrict__ wm1, const float* __restrict__ sm1, const float* __restrict__ bm1,
    float* __restrict__ a, float* __restrict__ bbuf, float* __restrict__ y16) {
    __shared__ SmA sm;
    const int t = threadIdx.x;
    stage_weights(sm, t, w1, w2, wm1);
    stage1_tile(sm, t, blockIdx.x, x, s1, b1, s2, b2, sm1, bm1, a, bbuf, y16);
}

__global__ __launch_bounds__(512, 4) void m2cv3_kernel(
    const float* __restrict__ y16, const float* __restrict__ a,
    const float* __restrict__ bbuf,
    const float* __restrict__ wm2, const float* __restrict__ sm2, const float* __restrict__ bm2,
    const float* __restrict__ wc, const float* __restrict__ sc, const float* __restrict__ bc,
    float* __restrict__ out) {
    __shared__ SmB sm;
    m2cv3_tile(sm, threadIdx.x, blockIdx.x, y16, a, bbuf, wm2, sm2, bm2,
               wc, sc, bc, out);
}

// ---------------------------------------------------------------------------
extern "C" void kernel_launch(void* const* d_in, const int* in_sizes, int n_in,
                              void* d_out, int out_size, void* d_ws, size_t ws_size,
                              hipStream_t stream) {
    const float* x    = (const float*)d_in[0];
    const float* cv1w = (const float*)d_in[1];
    const float* cv1s = (const float*)d_in[2];
    const float* cv1b = (const float*)d_in[3];
    const float* cv2w = (const float*)d_in[4];
    const float* cv2s = (const float*)d_in[5];
    const float* cv2b = (const float*)d_in[6];
    const float* m1w  = (const float*)d_in[7];
    const float* m1s  = (const float*)d_in[8];
    const float* m1b  = (const float*)d_in[9];
    const float* m2w  = (const float*)d_in[10];
    const float* m2s  = (const float*)d_in[11];
    const float* m2b  = (const float*)d_in[12];
    const float* cv3w = (const float*)d_in[13];
    const float* cv3s = (const float*)d_in[14];
    const float* cv3b = (const float*)d_in[15];

    float* ws   = (float*)d_ws;
    float* a    = ws;                 // 4*32*6400 = 819200
    float* bbuf = ws + 819200;        // 819200
    float* y16  = ws + 1638400;       // 409600 (end 2048000)
    float* outp = (float*)d_out;

    void* args[] = {
        (void*)&x,
        (void*)&cv1w, (void*)&cv1s, (void*)&cv1b,
        (void*)&cv2w, (void*)&cv2s, (void*)&cv2b,
        (void*)&m1w,  (void*)&m1s,  (void*)&m1b,
        (void*)&m2w,  (void*)&m2s,  (void*)&m2b,
        (void*)&cv3w, (void*)&cv3s, (void*)&cv3b,
        (void*)&a, (void*)&bbuf, (void*)&y16, (void*)&outp,
    };

    // Occupancy-derived grid (R13 lesson: hand arithmetic got rejected).
    bool done = false;
    int maxBlk = 0;
    hipError_t qe = hipOccupancyMaxActiveBlocksPerMultiprocessor(
        &maxBlk, (const void*)fused_kernel, 512, 0);
    if (qe == hipSuccess && maxBlk > 0) {
        int grid = maxBlk * 256;             // 256 CUs on MI355X
        if (grid > NTILE1) grid = NTILE1;
        hipError_t le = hipLaunchCooperativeKernel(
            (void*)fused_kernel, dim3(grid), dim3(512), args, 0, stream);
        done = (le == hipSuccess);
    }
    if (!done) {
        // deterministic fallback: two plain dispatches (R11/R12-equivalent)
        stage1_kernel<<<NTILE1, 512, 0, stream>>>(
            x, cv1w, cv1s, cv1b, cv2w, cv2s, cv2b, m1w, m1s, m1b, a, bbuf, y16);
        m2cv3_kernel<<<NTILE2, 512, 0, stream>>>(
            y16, a, bbuf, m2w, m2s, m2b, cv3w, cv3s, cv3b, outp);
    }
}

// Round 15
// 63.534 us; speedup vs baseline: 1.9574x; 1.9574x over previous
//
#include <hip/hip_runtime.h>
#include <math.h>

constexpr int B = 4, C = 64, H = 80, W = 80;
constexpr int HW = H * W;            // 6400
constexpr int NPIX = B * HW;         // 25600
constexpr int PXB = 16;              // pixels per stage1 tile
constexpr int NTILE1 = NPIX / PXB;   // 1600 stage1 tiles
constexpr int NBLK1  = 800;          // persistent blocks: 2 tiles each, all
                                     // co-resident (4 blk/CU LDS cap = 1024)
constexpr int NTILE2 = NPIX / 64;    // 400 m2cv3 tiles

typedef unsigned u32;

static __device__ __forceinline__ float silu(float v) {
    float e = __expf(-v);
    return v * __builtin_amdgcn_rcpf(1.0f + e);
}

// ---- packed u16 helpers (both GLCM channels in one instruction) -----------
static __device__ __forceinline__ u32 pks(u32 a, u32 b){u32 d; asm("v_pk_sub_u16 %0,%1,%2":"=v"(d):"v"(a),"v"(b)); return d;}
static __device__ __forceinline__ u32 pka(u32 a, u32 b){u32 d; asm("v_pk_add_u16 %0,%1,%2":"=v"(d):"v"(a),"v"(b)); return d;}
static __device__ __forceinline__ u32 pkm(u32 a, u32 b){u32 d; asm("v_pk_mul_lo_u16 %0,%1,%2":"=v"(d):"v"(a),"v"(b)); return d;}
static __device__ __forceinline__ u32 pkmin(u32 a, u32 b){u32 d; asm("v_pk_min_u16 %0,%1,%2":"=v"(d):"v"(a),"v"(b)); return d;}
static __device__ __forceinline__ u32 pkmaxi(u32 a, u32 b){u32 d; asm("v_pk_max_i16 %0,%1,%2":"=v"(d):"v"(a),"v"(b)); return d;}
static __device__ __forceinline__ float cb0(u32 a){float f; asm("v_cvt_f32_ubyte0 %0,%1":"=v"(f):"v"(a)); return f;}
static __device__ __forceinline__ float cb2(u32 a){float f; asm("v_cvt_f32_ubyte2 %0,%1":"=v"(f):"v"(a)); return f;}

// byte shuffle/LUT and byte-sum
static __device__ __forceinline__ u32 permb(u32 hi, u32 lo, u32 sel){
    u32 d; asm("v_perm_b32 %0, %1, %2, %3" : "=v"(d) : "v"(hi), "v"(lo), "v"(sel)); return d;}
static __device__ __forceinline__ u32 sad8(u32 a, u32 b, u32 c){
    u32 d; asm("v_sad_u8 %0, %1, %2, %3" : "=v"(d) : "v"(a), "v"(b), "v"(c)); return d;}

// packed compare-exchange: both u16 halves sorted independently (2 channels)
static __device__ __forceinline__ void ce(u32 &x, u32 &y) {
    u32 mn, mx;
    asm("v_pk_min_u16 %0, %2, %3\n\t"
        "v_pk_max_u16 %1, %2, %3"
        : "=&v"(mn), "=v"(mx) : "v"(x), "v"(y));
    x = mn; y = mx;
}

// ---------------------------------------------------------------------------
struct SmA {
    u32   qcell[32][3][18];                            // 6912 B
    float xs[PXB][76] __attribute__((aligned(16)));    // 4864 B
    float ws1[32][68] __attribute__((aligned(16)));    // 8704 B
    float ws2[32][68] __attribute__((aligned(16)));    // 8704 B
    float wsm1[16][32] __attribute__((aligned(16)));   // 2048 B
    float aT[PXB][33];                                 // 2112 B
    float red[8][PXB][4];                              // 2048 B
};                                                     // 35392 B -> 4 blk/CU
struct SmB {
    float ys[16][4][82];                               // 20992 B
    float a2[32][64];                                  // 8192 B
    float bs[32][64];                                  // 8192 B
};

static __device__ __forceinline__ void stage_weights(
    SmA& sm, int t,
    const float* __restrict__ w1, const float* __restrict__ w2,
    const float* __restrict__ wm1) {
    const float4* w1f = (const float4*)w1;
    const float4* w2f = (const float4*)w2;
    float4* s1f = (float4*)&sm.ws1[0][0];
    float4* s2f = (float4*)&sm.ws2[0][0];
    for (int e = t; e < 544; e += 512) { s1f[e] = w1f[e]; s2f[e] = w2f[e]; }
    if (t < 128) ((float4*)&sm.wsm1[0][0])[t] = ((const float4*)wm1)[t];
}

static __device__ __forceinline__ void stage1_tile(
    SmA& sm, int t, int tile,
    const float* __restrict__ x,
    const float* __restrict__ s1, const float* __restrict__ b1,
    const float* __restrict__ s2, const float* __restrict__ b2,
    const float* __restrict__ sm1, const float* __restrict__ bm1,
    float* __restrict__ a, float* __restrict__ bbuf, float* __restrict__ y16) {
    const int p0g = tile * PXB;
    const int bb  = p0g / HW;
    const int hw0 = p0g - bb * HW;
    const int h0  = hw0 / W;
    const int c0g = hw0 - h0 * W;

    // ---- A1: quantize stencil cells once, pack both channels ----
    for (int e = t; e < 32 * 3 * 18; e += 512) {
        const int grp = e / 54;
        const int rem = e - grp * 54;
        const int row = rem / 18;
        const int col = rem - row * 18;
        int gr = h0 + row - 1;  gr = gr < 0 ? 0 : (gr > H - 1 ? H - 1 : gr);
        int gc = c0g + col - 1; gc = gc < 0 ? 0 : (gc > W - 1 ? W - 1 : gc);
        const float v0 = x[((size_t)(bb * C + grp * 2)) * HW + gr * W + gc];
        const float v1 = x[((size_t)(bb * C + grp * 2 + 1)) * HW + gr * W + gc];
        int q0 = (int)(v0 * 7.0f); q0 = q0 < 0 ? 0 : (q0 > 7 ? 7 : q0);
        int q1 = (int)(v1 * 7.0f); q1 = q1 < 0 ? 0 : (q1 > 7 ? 7 : q1);
        sm.qcell[grp][row][col] = (u32)q0 | ((u32)q1 << 16);
        if (row == 1 && col >= 1 && col <= 16) {
            sm.xs[col - 1][grp * 2]     = v0;
            sm.xs[col - 1][grp * 2 + 1] = v1;
        }
    }
    __syncthreads();

    // ---- A2: GLCM packed-u16 core (perm/sad LUT for contrast+homog) ----
    const int pxl = t & 15;
    const int grp = t >> 4;
    u32 qpk[9];
    #pragma unroll
    for (int r = 0; r < 3; ++r)
        #pragma unroll
        for (int k = 0; k < 3; ++k)
            qpk[r * 3 + k] = sm.qcell[grp][r][pxl + k];

    static constexpr int PA[20] = {0,1,3,4,6,7, 0,1,2,3,4,5, 0,1,3,4, 1,2,4,5};
    static constexpr int PB[20] = {1,2,4,5,7,8, 3,4,5,6,7,8, 4,5,7,8, 3,4,6,7};

    const u32 ONEpk = 0x00010001u, EIGHTpk = 0x00080008u;
    u32 key[20];
    u32 csI = 0, hloI = 0, hhiI = 0;
    const u32 z0 = 0;
    #pragma unroll
    for (int j = 0; j < 10; ++j) {
        u32 adp0, adp1;
        {
            const u32 qa = qpk[PA[2*j]], qb = qpk[PB[2*j]];
            const u32 d = pks(qa, qb);
            adp0 = pkmaxi(d, pks(0u, d));
            key[2*j] = pka(pkm(qa, EIGHTpk), qb);
        }
        {
            const u32 qa = qpk[PA[2*j+1]], qb = qpk[PB[2*j+1]];
            const u32 d = pks(qa, qb);
            adp1 = pkmaxi(d, pks(0u, d));
            key[2*j+1] = pka(pkm(qa, EIGHTpk), qb);
        }
        const u32 pk4 = permb(adp1, adp0, 0x06040200u);
        csI  = sad8(permb(0x31241910u, 0x09040100u, pk4), z0, csI);
        hloI = sad8(permb(0x69788CA8u, 0xD218A448u, pk4), z0, hloI);
        hhiI = sad8(permb(0x00000000u, 0x00010103u, pk4), z0, hhiI);
    }

    #pragma unroll
    for (int p = 1; p < 32; p <<= 1) {
        #pragma unroll
        for (int k = p; k >= 1; k >>= 1) {
            const int jm = k % p;
            #pragma unroll
            for (int lo = 0; lo < 20; ++lo) {
                const int hi = lo + k;
                if (hi < 20 && lo >= jm && ((lo - jm) % (2 * k)) < k &&
                    (lo / (2 * p)) == (hi / (2 * p))) {
                    ce(key[lo], key[hi]);
                }
            }
        }
    }

    u32 eq[20];
    #pragma unroll
    for (int ai = 1; ai < 20; ++ai)
        eq[ai] = pks(ONEpk, pkmin(pks(key[ai], key[ai - 1]), ONEpk));

    u32 pc = 0, ps = 0, pv[20];
    pv[0] = 0;
    #pragma unroll
    for (int ai = 1; ai < 20; ++ai) {
        pc = pkm(pka(pc, ONEpk), eq[ai]);
        pv[ai] = pc;
        ps = pka(ps, pc);
    }
    float pr0, pr1;
    {
        const u32 m = pka(pv[19], ONEpk);
        pr0 = cb0(m); pr1 = cb2(m);
    }
    u32 rc = 0;
    #pragma unroll
    for (int ai = 18; ai >= 0; --ai) {
        rc = pkm(pka(rc, ONEpk), eq[ai + 1]);
        const u32 m = pka(pka(pv[ai], rc), ONEpk);
        pr0 *= cb0(m); pr1 *= cb2(m);
    }

    const int psum = (int)(ps & 0xFFFFu) + (int)(ps >> 16);
    const float lsum = __logf(pr0) + __logf(pr1);

    float fc = (float)csI * (1.f / 20.f);
    float fe = ((float)psum * 2.f + 40.f) * (1.f / 400.f);
    float fn = -(lsum + 40.f * -2.9957322736f) * (1.f / 20.f);
    float fh = (float)(hloI + (hhiI << 8)) * (1.f / 16800.f);

    fc += __shfl_xor(fc, 16); fe += __shfl_xor(fe, 16);
    fn += __shfl_xor(fn, 16); fh += __shfl_xor(fh, 16);
    fc += __shfl_xor(fc, 32); fe += __shfl_xor(fe, 32);
    fn += __shfl_xor(fn, 32); fh += __shfl_xor(fh, 32);
    const int wv = t >> 6;
    if ((t & 63) < 16) {
        sm.red[wv][pxl][0] = fc; sm.red[wv][pxl][1] = fe;
        sm.red[wv][pxl][2] = fn; sm.red[wv][pxl][3] = fh;
    }
    __syncthreads();
    if (t < 64) {
        const int p2 = t >> 2, f = t & 3;
        float s = 0.f;
        #pragma unroll
        for (int wq = 0; wq < 8; ++wq) s += sm.red[wq][p2][f];
        sm.xs[p2][64 + f] = s * (1.f / 64.f);
    }
    __syncthreads();

    // ---- A3: cv1 + cv2, thread = (px, oc); float4 LDS reads ----
    {
        const int px = t & 15;
        const int oc = t >> 4;
        float acc1 = 0.f, acc2 = 0.f;
        #pragma unroll
        for (int k = 0; k < 17; ++k) {
            const float4 xv = *reinterpret_cast<const float4*>(&sm.xs[px][k * 4]);
            const float4 wa = *reinterpret_cast<const float4*>(&sm.ws1[oc][k * 4]);
            const float4 wb = *reinterpret_cast<const float4*>(&sm.ws2[oc][k * 4]);
            acc1 += xv.x * wa.x + xv.y * wa.y + xv.z * wa.z + xv.w * wa.w;
            acc2 += xv.x * wb.x + xv.y * wb.y + xv.z * wb.z + xv.w * wb.w;
        }
        const int hw2 = hw0 + px;
        const float v1 = silu(acc1 * s1[oc] + b1[oc]);
        a[((size_t)(bb * 32 + oc)) * HW + hw2] = v1;
        sm.aT[px][oc] = v1;
        bbuf[((size_t)(bb * 32 + oc)) * HW + hw2] = silu(acc2 * s2[oc] + b2[oc]);
    }
    __syncthreads();

    // ---- A4: m1, thread = (px, oc16), first 256 threads ----
    if (t < 256) {
        const int px = t & 15;
        const int oc = t >> 4;
        float acc = 0.f;
        #pragma unroll 8
        for (int ic = 0; ic < 32; ++ic)
            acc += sm.aT[px][ic] * sm.wsm1[oc][ic];
        y16[((size_t)(bb * 16 + oc)) * HW + hw0 + px] = silu(acc * sm1[oc] + bm1[oc]);
    }
}

// ---------------------------------------------------------------------------
// Kernel 1: persistent balanced grid — 800 blocks, each runs tiles b and
// b+800. All blocks co-resident (LDS 35.4 KB -> 4 blk/CU = 1024 slots), so
// the 1600-block grid-tail (R11: 52% occupancy) disappears; weights staged
// once per block amortize over 2 tiles. Plain launch — coop fusion (R13/R14)
// is abandoned: grid.sync + residency constraints cost 3x.
// ---------------------------------------------------------------------------
__global__ __launch_bounds__(512, 4) void stage1_kernel(
    const float* __restrict__ x,
    const float* __restrict__ w1, const float* __restrict__ s1, const float* __restrict__ b1,
    const float* __restrict__ w2, const float* __restrict__ s2, const float* __restrict__ b2,
    const float* __restrict__ wm1, const float* __restrict__ sm1, const float* __restrict__ bm1,
    float* __restrict__ a, float* __restrict__ bbuf, float* __restrict__ y16) {
    __shared__ SmA sm;
    const int t = threadIdx.x;
    stage_weights(sm, t, w1, w2, wm1);
    stage1_tile(sm, t, blockIdx.x, x, s1, b1, s2, b2, sm1, bm1, a, bbuf, y16);
    __syncthreads();   // protect LDS (xs/qcell) before tile 2 overwrites
    stage1_tile(sm, t, blockIdx.x + NBLK1, x, s1, b1, s2, b2, sm1, bm1,
                a, bbuf, y16);
}

// ---------------------------------------------------------------------------
// Kernel 2: m2 (3x3, 16->32, pad 1) + BN + SiLU + residual, then cv3
// (1x1, 64->64). R11's proven 8-wave structure, 400 blocks.
// ---------------------------------------------------------------------------
__global__ __launch_bounds__(512, 4) void m2cv3_kernel(
    const float* __restrict__ y16, const float* __restrict__ a,
    const float* __restrict__ bbuf,
    const float* __restrict__ wm2, const float* __restrict__ sm2, const float* __restrict__ bm2,
    const float* __restrict__ wc, const float* __restrict__ sc, const float* __restrict__ bc,
    float* __restrict__ out) {
    __shared__ SmB sm;
    const int t = threadIdx.x;
    const int p0 = blockIdx.x * 64;
    const int bi = p0 / HW;
    const int hw0 = p0 - bi * HW;
    const int h0 = hw0 / W;

    const float* yb = y16 + (size_t)(bi * 16) * HW;
    for (int e = t; e < 16 * 4 * 82; e += 512) {
        const int ch = e / 328;
        const int rem = e - ch * 328;
        const int row = rem / 82;
        const int col = rem - row * 82;
        const int r = h0 - 1 + row;
        const int c = col - 1;
        float v = 0.f;
        if ((unsigned)r < (unsigned)H && (unsigned)c < (unsigned)W)
            v = yb[(size_t)ch * HW + r * W + c];
        sm.ys[ch][row][col] = v;
    }
    for (int e = t; e < 32 * 64; e += 512) {
        const int ic = e >> 6, px = e & 63;
        sm.bs[ic][px] = bbuf[((size_t)(bi * 32 + ic)) * HW + hw0 + px];
    }
    __syncthreads();

    const int lane = t & 63;
    const int wv = __builtin_amdgcn_readfirstlane(t >> 6);
    const int hw = hw0 + lane;
    const int h = hw / W;
    const int w = hw - h * W;
    const int lr = h - h0;
    const int oc0 = wv * 4;

    float acc[4] = {0.f, 0.f, 0.f, 0.f};
    #pragma unroll 2
    for (int ic = 0; ic < 16; ++ic) {
        #pragma unroll
        for (int ky = 0; ky < 3; ++ky) {
            #pragma unroll
            for (int kx = 0; kx < 3; ++kx) {
                const float v = sm.ys[ic][lr + ky][w + kx];
                const int tap = ic * 9 + ky * 3 + kx;
                #pragma unroll
                for (int j = 0; j < 4; ++j)
                    acc[j] += v * wm2[(oc0 + j) * 144 + tap];
            }
        }
    }
    #pragma unroll
    for (int j = 0; j < 4; ++j) {
        const int oc = oc0 + j;
        sm.a2[oc][lane] = a[((size_t)(bi * 32 + oc)) * HW + hw]
                        + silu(acc[j] * sm2[oc] + bm2[oc]);
    }
    __syncthreads();
    const int oc3 = wv * 8;
    float c_[8] = {0.f, 0.f, 0.f, 0.f, 0.f, 0.f, 0.f, 0.f};
    #pragma unroll 4
    for (int ic = 0; ic < 32; ++ic) {
        const float av = sm.a2[ic][lane];
        const float bv = sm.bs[ic][lane];
        #pragma unroll
        for (int j = 0; j < 8; ++j) {
            c_[j] += av * wc[(oc3 + j) * 64 + ic];
            c_[j] += bv * wc[(oc3 + j) * 64 + 32 + ic];
        }
    }
    #pragma unroll
    for (int j = 0; j < 8; ++j) {
        const int oc = oc3 + j;
        out[((size_t)(bi * 64 + oc)) * HW + hw] = silu(c_[j] * sc[oc] + bc[oc]);
    }
}

// ---------------------------------------------------------------------------
extern "C" void kernel_launch(void* const* d_in, const int* in_sizes, int n_in,
                              void* d_out, int out_size, void* d_ws, size_t ws_size,
                              hipStream_t stream) {
    const float* x    = (const float*)d_in[0];
    const float* cv1w = (const float*)d_in[1];
    const float* cv1s = (const float*)d_in[2];
    const float* cv1b = (const float*)d_in[3];
    const float* cv2w = (const float*)d_in[4];
    const float* cv2s = (const float*)d_in[5];
    const float* cv2b = (const float*)d_in[6];
    const float* m1w  = (const float*)d_in[7];
    const float* m1s  = (const float*)d_in[8];
    const float* m1b  = (const float*)d_in[9];
    const float* m2w  = (const float*)d_in[10];
    const float* m2s  = (const float*)d_in[11];
    const float* m2b  = (const float*)d_in[12];
    const float* cv3w = (const float*)d_in[13];
    const float* cv3s = (const float*)d_in[14];
    const float* cv3b = (const float*)d_in[15];

    float* ws   = (float*)d_ws;
    float* a    = ws;                 // 4*32*6400 = 819200
    float* bbuf = ws + 819200;        // 819200
    float* y16  = ws + 1638400;       // 409600 (end 2048000)

    stage1_kernel<<<NBLK1, 512, 0, stream>>>(
        x, cv1w, cv1s, cv1b, cv2w, cv2s, cv2b, m1w, m1s, m1b, a, bbuf, y16);
    m2cv3_kernel<<<NTILE2, 512, 0, stream>>>(
        y16, a, bbuf, m2w, m2s, m2b, cv3w, cv3s, cv3b, (float*)d_out);
}